// Round 1
// baseline (136.022 us; speedup 1.0000x reference)
//
#include <hip/hip_runtime.h>

#define NROWS 4096
#define VCOLS 30522
#define PAD   512
#define V2    (VCOLS / 2)   // 15261 float2 per row (VCOLS is even)
#define BLOCK 256

__global__ __launch_bounds__(BLOCK) void sparse_compact_kernel(
    const float* __restrict__ in, float* __restrict__ out)
{
    const int row  = blockIdx.x;
    const int tid  = threadIdx.x;
    const int lane = tid & 63;
    const int wid  = tid >> 6;

    float* orow = out + (size_t)row * (2 * PAD);

    // Zero this row's output (padding slots must be 0; d_out is poisoned).
    #pragma unroll
    for (int i = tid; i < 2 * PAD; i += BLOCK) orow[i] = 0.0f;
    __syncthreads();

    const float2* irow =
        reinterpret_cast<const float2*>(in + (size_t)row * VCOLS);

    __shared__ int wtot[4];
    int base = 0;  // block-uniform running count of nonzeros emitted

    for (int c0 = 0; c0 < V2; c0 += BLOCK) {
        const int idx = c0 + tid;  // float2 index within the row
        float2 v = make_float2(0.0f, 0.0f);
        if (idx < V2) v = irow[idx];

        const bool p0 = (v.x != 0.0f);
        const bool p1 = (v.y != 0.0f);

        const unsigned long long b0 = __ballot(p0);
        const unsigned long long b1 = __ballot(p1);
        const unsigned long long lm = (1ull << lane) - 1ull;

        const int pre = __popcll(b0 & lm) + __popcll(b1 & lm);
        const int tot = __popcll(b0) + __popcll(b1);

        if (lane == 0) wtot[wid] = tot;
        __syncthreads();

        int wbase = base;
        #pragma unroll
        for (int w = 0; w < 3; ++w) { if (w < wid) wbase += wtot[w]; }
        const int tot_all = wtot[0] + wtot[1] + wtot[2] + wtot[3];

        const int d0 = wbase + pre;
        if (p0 && d0 < PAD) {
            orow[d0]       = (float)(2 * idx);
            orow[PAD + d0] = v.x;
        }
        const int d1 = d0 + (p0 ? 1 : 0);
        if (p1 && d1 < PAD) {
            orow[d1]       = (float)(2 * idx + 1);
            orow[PAD + d1] = v.y;
        }

        base += tot_all;
        __syncthreads();           // protect wtot reuse next iteration
        if (base >= PAD) break;    // block-uniform; all remaining dests >= PAD
    }
}

extern "C" void kernel_launch(void* const* d_in, const int* in_sizes, int n_in,
                              void* d_out, int out_size, void* d_ws, size_t ws_size,
                              hipStream_t stream)
{
    const float* in = (const float*)d_in[0];
    float* out = (float*)d_out;
    sparse_compact_kernel<<<NROWS, BLOCK, 0, stream>>>(in, out);
}

// Round 2
// 131.554 us; speedup vs baseline: 1.0340x; 1.0340x over previous
//
#include <hip/hip_runtime.h>

#define NROWS 4096
#define VCOLS 30522
#define PAD   512
#define NF4   7630      // aligned float4 chunks per row after head/tail peel
#define NIT   120       // ceil(7630/64)
#define BLOCK 256
#define ROWS_PER_BLOCK 4

__device__ __forceinline__ int lanes_below(unsigned long long m) {
    // popcount of m restricted to lanes strictly below this lane (2 VALU ops)
    int c = __builtin_amdgcn_mbcnt_lo((unsigned)m, 0u);
    return __builtin_amdgcn_mbcnt_hi((unsigned)(m >> 32), c);
}

__global__ __launch_bounds__(BLOCK) void sparse_compact_wave(
    const float* __restrict__ in, float* __restrict__ out)
{
    const int tid  = threadIdx.x;
    const int lane = tid & 63;
    const int wid  = tid >> 6;
    const int row  = blockIdx.x * ROWS_PER_BLOCK + wid;

    float* orow = out + (size_t)row * (2 * PAD);
    const float* rbase = in + (size_t)row * VCOLS;
    const int odd = row & 1;

    int base = 0;

    // Head peel (odd rows start 8 mod 16): cols 0,1. All lanes load the same
    // address (HW broadcast, one transaction) so `base` stays wave-uniform.
    if (odd) {
        float2 h = *reinterpret_cast<const float2*>(rbase);
        int n0 = (h.x != 0.0f), n1 = (h.y != 0.0f);
        if (lane == 0) {
            if (n0) { orow[0]  = 0.0f; orow[PAD]      = h.x; }
            if (n1) { orow[n0] = 1.0f; orow[PAD + n0] = h.y; }
        }
        base = n0 + n1;
    }
    const int coff = odd ? 2 : 0;
    const float4* irow4 = reinterpret_cast<const float4*>(rbase + coff);

    const float4 z = make_float4(0.0f, 0.0f, 0.0f, 0.0f);

    // 2-deep software pipeline over 7630 float4s (16B/lane, 1KB/wave/iter).
    int idx = lane;
    float4 cur = (idx < NF4) ? irow4[idx] : z;
    for (int it = 0; it < NIT; ++it) {
        const int nidx = idx + 64;
        float4 nxt = (nidx < NF4) ? irow4[nidx] : z;

        const bool p0 = (cur.x != 0.0f);
        const bool p1 = (cur.y != 0.0f);
        const bool p2 = (cur.z != 0.0f);
        const bool p3 = (cur.w != 0.0f);

        const unsigned long long b0 = __ballot(p0);
        const unsigned long long b1 = __ballot(p1);
        const unsigned long long b2 = __ballot(p2);
        const unsigned long long b3 = __ballot(p3);

        // nonzeros in lanes below me (all 4 elems precede my elems in col order)
        int d = base + lanes_below(b0) + lanes_below(b1)
                     + lanes_below(b2) + lanes_below(b3);
        const int tot = __popcll(b0) + __popcll(b1) + __popcll(b2) + __popcll(b3);

        const int c = coff + 4 * idx;
        if (p0 && d < PAD) { orow[d] = (float)c;       orow[PAD + d] = cur.x; } d += p0;
        if (p1 && d < PAD) { orow[d] = (float)(c + 1); orow[PAD + d] = cur.y; } d += p1;
        if (p2 && d < PAD) { orow[d] = (float)(c + 2); orow[PAD + d] = cur.z; } d += p2;
        if (p3 && d < PAD) { orow[d] = (float)(c + 3); orow[PAD + d] = cur.w; } d += p3;

        base += tot;
        if (base >= PAD) break;   // wave-uniform; all later dests >= PAD
        cur = nxt;
        idx = nidx;
    }

    // Tail peel (even rows): cols 30520, 30521. Uniform load, lane 0 writes.
    if (!odd && base < PAD) {
        float2 t = *reinterpret_cast<const float2*>(rbase + 30520);
        int n0 = (t.x != 0.0f), n1 = (t.y != 0.0f);
        if (lane == 0) {
            if (n0)              { orow[base]      = 30520.0f; orow[PAD + base]      = t.x; }
            int d = base + n0;
            if (n1 && d < PAD)   { orow[d]         = 30521.0f; orow[PAD + d]         = t.y; }
        }
        base += n0 + n1;
    }

    // Zero only the padding slots (d_out is poisoned; scatter covered [0,base)).
    const int zstart = (base < PAD) ? base : PAD;
    for (int i = zstart + lane; i < PAD; i += 64) {
        orow[i]       = 0.0f;
        orow[PAD + i] = 0.0f;
    }
}

extern "C" void kernel_launch(void* const* d_in, const int* in_sizes, int n_in,
                              void* d_out, int out_size, void* d_ws, size_t ws_size,
                              hipStream_t stream)
{
    const float* in = (const float*)d_in[0];
    float* out = (float*)d_out;
    sparse_compact_wave<<<NROWS / ROWS_PER_BLOCK, BLOCK, 0, stream>>>(in, out);
}

// Round 3
// 120.348 us; speedup vs baseline: 1.1302x; 1.0931x over previous
//
#include <hip/hip_runtime.h>

#define NROWS 4096
#define VCOLS 30522
#define PAD   512
#define NF4   7630      // aligned float4 chunks per row after head/tail peel
#define NIT   120       // ceil(7630/64); 120 = 30 groups x 4 steps
#define BLOCK 256
#define ROWS_PER_BLOCK 4
#define DEPTH 4         // outstanding float4 prefetches per wave

__device__ __forceinline__ int lanes_below(unsigned long long m) {
    int c = __builtin_amdgcn_mbcnt_lo((unsigned)m, 0u);
    return __builtin_amdgcn_mbcnt_hi((unsigned)(m >> 32), c);
}

__global__ __launch_bounds__(BLOCK) void sparse_compact_wave(
    const float* __restrict__ in, float* __restrict__ out)
{
    const int tid  = threadIdx.x;
    const int lane = tid & 63;
    const int wid  = tid >> 6;
    const int row  = blockIdx.x * ROWS_PER_BLOCK + wid;

    float* orow = out + (size_t)row * (2 * PAD);
    const float* rbase = in + (size_t)row * VCOLS;
    const int odd = row & 1;

    int base = 0;

    // Head peel (odd rows start 8 mod 16): cols 0,1. Uniform load -> broadcast.
    if (odd) {
        float2 h = *reinterpret_cast<const float2*>(rbase);
        int n0 = (h.x != 0.0f), n1 = (h.y != 0.0f);
        if (lane == 0) {
            if (n0) { orow[0]  = 0.0f; orow[PAD]      = h.x; }
            if (n1) { orow[n0] = 1.0f; orow[PAD + n0] = h.y; }
        }
        base = n0 + n1;
    }
    const int coff = odd ? 2 : 0;
    const float4* irow4 = reinterpret_cast<const float4*>(rbase + coff);

    const float4 z = make_float4(0.0f, 0.0f, 0.0f, 0.0f);

    // 4-deep software pipeline: 4 outstanding 1KB wave-loads at all times.
    int idx = lane;  // chunk index of the OLDEST in-flight register
    float4 c0 = (idx           < NF4) ? irow4[idx]           : z;
    float4 c1 = (idx + 64      < NF4) ? irow4[idx + 64]      : z;
    float4 c2 = (idx + 128     < NF4) ? irow4[idx + 128]     : z;
    float4 c3 = (idx + 192     < NF4) ? irow4[idx + 192]     : z;

#define STEP(CREG)                                                         \
    do {                                                                   \
        const int pidx = idx + DEPTH * 64;                                 \
        float4 nv = (pidx < NF4) ? irow4[pidx] : z;                        \
        const bool p0 = (CREG.x != 0.0f);                                  \
        const bool p1 = (CREG.y != 0.0f);                                  \
        const bool p2 = (CREG.z != 0.0f);                                  \
        const bool p3 = (CREG.w != 0.0f);                                  \
        const unsigned long long b0 = __ballot(p0);                        \
        const unsigned long long b1 = __ballot(p1);                        \
        const unsigned long long b2 = __ballot(p2);                        \
        const unsigned long long b3 = __ballot(p3);                        \
        int d = base + lanes_below(b0) + lanes_below(b1)                   \
                     + lanes_below(b2) + lanes_below(b3);                  \
        const int tot = __popcll(b0) + __popcll(b1)                        \
                      + __popcll(b2) + __popcll(b3);                       \
        const int c = coff + 4 * idx;                                      \
        if (p0 && d < PAD) { orow[d] = (float)c;       orow[PAD + d] = CREG.x; } d += p0; \
        if (p1 && d < PAD) { orow[d] = (float)(c + 1); orow[PAD + d] = CREG.y; } d += p1; \
        if (p2 && d < PAD) { orow[d] = (float)(c + 2); orow[PAD + d] = CREG.z; } d += p2; \
        if (p3 && d < PAD) { orow[d] = (float)(c + 3); orow[PAD + d] = CREG.w; } d += p3; \
        base += tot;                                                       \
        CREG = nv;                                                         \
        idx += 64;                                                         \
    } while (0)

    for (int g = 0; g < NIT / DEPTH; ++g) {
        STEP(c0);
        STEP(c1);
        STEP(c2);
        STEP(c3);
        if (base >= PAD) break;   // wave-uniform; all later dests >= PAD
    }
#undef STEP

    // Tail peel (even rows): cols 30520, 30521. Uniform load, lane 0 writes.
    if (!odd && base < PAD) {
        float2 t = *reinterpret_cast<const float2*>(rbase + 30520);
        int n0 = (t.x != 0.0f), n1 = (t.y != 0.0f);
        if (lane == 0) {
            if (n0)            { orow[base] = 30520.0f; orow[PAD + base] = t.x; }
            int d = base + n0;
            if (n1 && d < PAD) { orow[d]    = 30521.0f; orow[PAD + d]    = t.y; }
        }
        base += n0 + n1;
    }

    // Zero only the padding slots (d_out is poisoned; scatter covered [0,base)).
    const int zstart = (base < PAD) ? base : PAD;
    for (int i = zstart + lane; i < PAD; i += 64) {
        orow[i]       = 0.0f;
        orow[PAD + i] = 0.0f;
    }
}

extern "C" void kernel_launch(void* const* d_in, const int* in_sizes, int n_in,
                              void* d_out, int out_size, void* d_ws, size_t ws_size,
                              hipStream_t stream)
{
    const float* in = (const float*)d_in[0];
    float* out = (float*)d_out;
    sparse_compact_wave<<<NROWS / ROWS_PER_BLOCK, BLOCK, 0, stream>>>(in, out);
}

// Round 4
// 100.601 us; speedup vs baseline: 1.3521x; 1.1963x over previous
//
#include <hip/hip_runtime.h>

#define NROWS 4096
#define VCOLS 30522
#define PAD   512
#define NF4   7630        // aligned float4 chunks per row after head/tail peel
#define BLOCK 256
#define RPB   4           // rows (= waves) per block
#define DEPTH 8           // outstanding 1KB wave-loads
#define MAIN_GROUPS 14    // 14*8 = 112 main iters; +8 epilogue = 120 total

__device__ __forceinline__ int lanes_below(unsigned long long m) {
    int c = __builtin_amdgcn_mbcnt_lo((unsigned)m, 0u);
    return __builtin_amdgcn_mbcnt_hi((unsigned)(m >> 32), c);
}

__global__ __launch_bounds__(BLOCK) void sparse_compact_wave(
    const float* __restrict__ in, float* __restrict__ out)
{
    __shared__ float2 sbuf[RPB][PAD];   // per-wave staging: {col, val}, 16KB/block

    const int tid  = threadIdx.x;
    const int lane = tid & 63;
    const int wid  = tid >> 6;
    const int row  = blockIdx.x * RPB + wid;

    float* orow = out + (size_t)row * (2 * PAD);
    const float* rbase = in + (size_t)row * VCOLS;
    const int odd = row & 1;

    int base = 0;

    // Head peel (odd rows start 8 mod 16): cols 0,1. Uniform load -> broadcast.
    if (odd) {
        float2 h = *reinterpret_cast<const float2*>(rbase);
        int n0 = (h.x != 0.0f), n1 = (h.y != 0.0f);
        if (lane == 0) {
            if (n0) sbuf[wid][0]  = make_float2(0.0f, h.x);
            if (n1) sbuf[wid][n0] = make_float2(1.0f, h.y);
        }
        base = n0 + n1;
    }
    const int coff = odd ? 2 : 0;
    const float4* irow4 = reinterpret_cast<const float4*>(rbase + coff);
    const float4 z = make_float4(0.0f, 0.0f, 0.0f, 0.0f);

    // 8-deep pipeline prologue: iters 0..7 all fully in-bounds (511 < 7630).
    int idx = lane;     // chunk index of the oldest in-flight register
    float4 c0 = irow4[idx];
    float4 c1 = irow4[idx + 64];
    float4 c2 = irow4[idx + 128];
    float4 c3 = irow4[idx + 192];
    float4 c4 = irow4[idx + 256];
    float4 c5 = irow4[idx + 320];
    float4 c6 = irow4[idx + 384];
    float4 c7 = irow4[idx + 448];

    // Consume one chunk: ballot scan + conditional LDS scatter (lgkmcnt only,
    // keeps vmcnt clean for the load pipeline).
#define CONSUME(CREG)                                                        \
    do {                                                                     \
        const bool p0 = (CREG.x != 0.0f);                                    \
        const bool p1 = (CREG.y != 0.0f);                                    \
        const bool p2 = (CREG.z != 0.0f);                                    \
        const bool p3 = (CREG.w != 0.0f);                                    \
        const unsigned long long b0 = __ballot(p0);                          \
        const unsigned long long b1 = __ballot(p1);                          \
        const unsigned long long b2 = __ballot(p2);                          \
        const unsigned long long b3 = __ballot(p3);                          \
        int d = base + lanes_below(b0) + lanes_below(b1)                     \
                     + lanes_below(b2) + lanes_below(b3);                    \
        const int tot = __popcll(b0) + __popcll(b1)                          \
                      + __popcll(b2) + __popcll(b3);                         \
        const float cf = (float)(coff + 4 * idx);                            \
        if (p0 && d < PAD) sbuf[wid][d] = make_float2(cf,        CREG.x); d += p0; \
        if (p1 && d < PAD) sbuf[wid][d] = make_float2(cf + 1.0f, CREG.y); d += p1; \
        if (p2 && d < PAD) sbuf[wid][d] = make_float2(cf + 2.0f, CREG.z); d += p2; \
        if (p3 && d < PAD) sbuf[wid][d] = make_float2(cf + 3.0f, CREG.w);          \
        base += tot;                                                         \
    } while (0)

    // Main-loop step: unconditional clamped prefetch keeps vmcnt static.
#define STEP(CREG)                                                           \
    do {                                                                     \
        const int pidx = idx + DEPTH * 64;                                   \
        const int pc = (pidx < NF4) ? pidx : (NF4 - 1);                      \
        float4 nv = irow4[pc];                                               \
        CONSUME(CREG);                                                       \
        CREG = nv;                                                           \
        idx += 64;                                                           \
    } while (0)

    // Epilogue step: no prefetch; zero lanes past end of row.
#define STEP_E(CREG)                                                         \
    do {                                                                     \
        if (idx >= NF4) CREG = z;                                            \
        CONSUME(CREG);                                                       \
        idx += 64;                                                           \
    } while (0)

    for (int g = 0; g < MAIN_GROUPS; ++g) {
        STEP(c0); STEP(c1); STEP(c2); STEP(c3);
        STEP(c4); STEP(c5); STEP(c6); STEP(c7);
        if (base >= PAD) break;   // wave-uniform; all later dests >= PAD
    }
    if (base < PAD) {
        STEP_E(c0); STEP_E(c1); STEP_E(c2); STEP_E(c3);
        STEP_E(c4); STEP_E(c5); STEP_E(c6); STEP_E(c7);
    }
#undef STEP
#undef STEP_E
#undef CONSUME

    // Tail peel (even rows): cols 30520, 30521. Uniform load, lane 0 writes.
    if (!odd && base < PAD) {
        float2 t = *reinterpret_cast<const float2*>(rbase + 30520);
        int n0 = (t.x != 0.0f), n1 = (t.y != 0.0f);
        if (lane == 0) {
            if (n0) sbuf[wid][base] = make_float2(30520.0f, t.x);
            const int dd = base + n0;
            if (n1 && dd < PAD) sbuf[wid][dd] = make_float2(30521.0f, t.y);
        }
        base += n0 + n1;
    }

    __syncthreads();   // drain LDS writes (also covers same-wave write->read)

    // Coalesced flush: deinterleave {col,val} -> [0..511]=cols, [512..1023]=vals.
    // Slots >= base were never written (LDS garbage) -> masked to 0, which also
    // implements the zero-padding (d_out is poisoned by the harness).
    const int nb = (base < PAD) ? base : PAD;
    #pragma unroll
    for (int k = 0; k < 2; ++k) {
        const int sb = k * 256 + lane * 4;
        const float4 ab = *reinterpret_cast<const float4*>(&sbuf[wid][sb]);     // slots sb, sb+1
        const float4 cd = *reinterpret_cast<const float4*>(&sbuf[wid][sb + 2]); // slots sb+2, sb+3
        float4 iv = make_float4(sb     < nb ? ab.x : 0.0f,
                                sb + 1 < nb ? ab.z : 0.0f,
                                sb + 2 < nb ? cd.x : 0.0f,
                                sb + 3 < nb ? cd.z : 0.0f);
        float4 vv = make_float4(sb     < nb ? ab.y : 0.0f,
                                sb + 1 < nb ? ab.w : 0.0f,
                                sb + 2 < nb ? cd.y : 0.0f,
                                sb + 3 < nb ? cd.w : 0.0f);
        *reinterpret_cast<float4*>(&orow[sb])       = iv;
        *reinterpret_cast<float4*>(&orow[PAD + sb]) = vv;
    }
}

extern "C" void kernel_launch(void* const* d_in, const int* in_sizes, int n_in,
                              void* d_out, int out_size, void* d_ws, size_t ws_size,
                              hipStream_t stream)
{
    const float* in = (const float*)d_in[0];
    float* out = (float*)d_out;
    sparse_compact_wave<<<NROWS / RPB, BLOCK, 0, stream>>>(in, out);
}

// Round 5
// 100.199 us; speedup vs baseline: 1.3575x; 1.0040x over previous
//
#include <hip/hip_runtime.h>

#define NROWS 4096
#define VCOLS 30522
#define PAD   512
#define NF4   7630      // aligned float4 chunks per row after head/tail peel
#define BLOCK 256
#define WPB   4         // waves per block = segments per row
#define QCH   1908      // float4 chunks per segment (4*1908 = 7632 >= 7630)
#define NITW  32        // padded iters per wave (32*64 = 2048 >= 1908), /4 = 8 groups
#define DEPTH 4         // outstanding 1KB wave-loads per wave

__device__ __forceinline__ int lanes_below(unsigned long long m) {
    int c = __builtin_amdgcn_mbcnt_lo((unsigned)m, 0u);
    return __builtin_amdgcn_mbcnt_hi((unsigned)(m >> 32), c);
}

__global__ __launch_bounds__(BLOCK, 8) void sparse_compact_block(
    const float* __restrict__ in, float* __restrict__ out)
{
    __shared__ float2 sbuf[WPB][PAD];   // per-wave segment staging {col,val}, 16KB
    __shared__ int scnt[WPB];

    const int tid  = threadIdx.x;
    const int lane = tid & 63;
    const int wid  = tid >> 6;
    const int row  = blockIdx.x;

    float* orow = out + (size_t)row * (2 * PAD);
    const float* rbase = in + (size_t)row * VCOLS;
    const int odd = row & 1;
    const int coff = odd ? 2 : 0;
    const float4* irow4 = reinterpret_cast<const float4*>(rbase + coff);

    int base = 0;

    // Head peel (odd rows start 8 mod 16): cols 0,1 belong to wave 0's segment.
    // Uniform load -> broadcast; base stays wave-uniform.
    if (odd && wid == 0) {
        float2 h = *reinterpret_cast<const float2*>(rbase);
        int n0 = (h.x != 0.0f), n1 = (h.y != 0.0f);
        if (lane == 0) {
            if (n0) sbuf[0][0]  = make_float2(0.0f, h.x);
            if (n1) sbuf[0][n0] = make_float2(1.0f, h.y);
        }
        base = n0 + n1;
    }

    const int segStart = wid * QCH;
    const int segEnd   = (segStart + QCH < NF4) ? segStart + QCH : NF4;

    // 4-deep pipeline prologue (first 256 chunks of every segment are in range).
    int idx = segStart + lane;
    float4 c0 = irow4[idx];
    float4 c1 = irow4[idx + 64];
    float4 c2 = irow4[idx + 128];
    float4 c3 = irow4[idx + 192];

#define STEP(CREG)                                                            \
    do {                                                                      \
        int pidx = idx + DEPTH * 64;                                          \
        if (pidx >= NF4) pidx = NF4 - 1;   /* clamp: keeps vmcnt static */    \
        float4 nv = irow4[pidx];                                              \
        const bool pv = (idx < segEnd);                                       \
        const bool p0 = pv && (CREG.x != 0.0f);                               \
        const bool p1 = pv && (CREG.y != 0.0f);                               \
        const bool p2 = pv && (CREG.z != 0.0f);                               \
        const bool p3 = pv && (CREG.w != 0.0f);                               \
        const unsigned long long b0 = __ballot(p0);                           \
        const unsigned long long b1 = __ballot(p1);                           \
        const unsigned long long b2 = __ballot(p2);                           \
        const unsigned long long b3 = __ballot(p3);                           \
        int d = base + lanes_below(b0) + lanes_below(b1)                      \
                     + lanes_below(b2) + lanes_below(b3);                     \
        const int tot = __popcll(b0) + __popcll(b1)                           \
                      + __popcll(b2) + __popcll(b3);                          \
        const float cf = (float)(coff + 4 * idx);                             \
        if (p0 && d < PAD) sbuf[wid][d] = make_float2(cf,        CREG.x); d += p0; \
        if (p1 && d < PAD) sbuf[wid][d] = make_float2(cf + 1.0f, CREG.y); d += p1; \
        if (p2 && d < PAD) sbuf[wid][d] = make_float2(cf + 2.0f, CREG.z); d += p2; \
        if (p3 && d < PAD) sbuf[wid][d] = make_float2(cf + 3.0f, CREG.w);          \
        base += tot;                                                          \
        CREG = nv;                                                            \
        idx += 64;                                                            \
    } while (0)

    for (int g = 0; g < NITW / DEPTH; ++g) {
        STEP(c0); STEP(c1); STEP(c2); STEP(c3);
        if (base >= PAD) break;   // wave-uniform; segment buffer full (capped)
    }
#undef STEP

    // Tail peel (even rows): cols 30520, 30521 belong to wave 3's segment.
    if (!odd && wid == (WPB - 1) && base < PAD) {
        float2 t = *reinterpret_cast<const float2*>(rbase + 30520);
        int n0 = (t.x != 0.0f), n1 = (t.y != 0.0f);
        if (lane == 0) {
            if (n0) sbuf[wid][base] = make_float2(30520.0f, t.x);
            const int dd = base + n0;
            if (n1 && dd < PAD) sbuf[wid][dd] = make_float2(30521.0f, t.y);
        }
        base += n0 + n1;
    }

    if (lane == 0) scnt[wid] = (base < PAD) ? base : PAD;  // capped count
    __syncthreads();

    // Merge: prefix over capped segment counts, then gather + coalesced write.
    const int n0 = scnt[0], n1 = scnt[1], n2 = scnt[2], n3 = scnt[3];
    const int cum1 = n0;
    const int cum2 = cum1 + n1;
    const int cum3 = cum2 + n2;
    int total = cum3 + n3;
    if (total > PAD) total = PAD;

    // 512 slots, 2 consecutive per thread -> float2 stores for cols and vals.
    const int i0 = 2 * tid;
    float2 cols, vals;
    #pragma unroll
    for (int k = 0; k < 2; ++k) {
        const int i = i0 + k;
        float c = 0.0f, v = 0.0f;
        if (i < total) {
            const int s = (i >= cum1) + (i >= cum2) + (i >= cum3);
            const int off = i - (s == 0 ? 0 : (s == 1 ? cum1 : (s == 2 ? cum2 : cum3)));
            const float2 e = sbuf[s][off];
            c = e.x; v = e.y;
        }
        if (k == 0) { cols.x = c; vals.x = v; } else { cols.y = c; vals.y = v; }
    }
    *reinterpret_cast<float2*>(&orow[i0])       = cols;
    *reinterpret_cast<float2*>(&orow[PAD + i0]) = vals;
}

extern "C" void kernel_launch(void* const* d_in, const int* in_sizes, int n_in,
                              void* d_out, int out_size, void* d_ws, size_t ws_size,
                              hipStream_t stream)
{
    const float* in = (const float*)d_in[0];
    float* out = (float*)d_out;
    sparse_compact_block<<<NROWS, BLOCK, 0, stream>>>(in, out);
}